// Round 10
// baseline (524.139 us; speedup 1.0000x reference)
//
#include <hip/hip_runtime.h>
#include <math.h>

// ---------------------------------------------------------------------------
// EncoderGPECls: kNN(16) -> PCA curvature blend -> adaptive GPE embeddings
// xyz: [8,4096,3] f32  ->  out: [8,4096,128] f32
//
// R9: x-sorted windowed kNN at R7 occupancy (R6's idea, R7's shell).
//   presort: per-batch bitonic by x (1024 thr, R6-proven) + double stats.
//   knn: 512 blocks x 256 thr (2 blocks/CU, 8 waves/CU). All 4 waves serve
//     the same 64 x-contiguous queries (one sorted chunk). Wave 0 scans the
//     home chunk, shares per-query thr (17th-of-chunk >= true r17, subset
//     bound) via LDS; waves 1-3 own disjoint outward chunks (offset mod 4,
//     wave 0 gets mod-0 to offset its home-chunk work). Direction closes on
//     __all(gap^2 >= thr) -- exact (sorted x => d2 >= gap^2).
//   Why: R7 accounting showed ~56k of 71k instr/wave is ~750 wave-wide
//     inserts (8x the ~90 minimum) because random candidate order keeps maxv
//     loose. Near-first order collapses both scan volume (~4x) and inserts.
//   Serial argmax kept (R8 tree: +24% issue, slower). Transposed buffers
//   (conflict-free, 2x proven). Parallel finalize folded in out (R8-neutral).
//
// ws float layout:
//   [0, 32768)            curv per point
//   [32768, 131072)       rasig2 (3 SoA planes of 32768)
//   [131072, 131080)      curv batch sums (atomic, zeroed via memsetAsync)
//   [131080, 131176)      per-batch raw sums as 48 DOUBLES
//   [131184, 262256)      sorted float4 (x,y,z,orig_idx) per batch
// ---------------------------------------------------------------------------

#define NPTS 4096
#define KNN 17          // 16 neighbors + self (self contributes zero to sums)
#define CAP 8           // append slots per lane (transposed layout)
#define BLKT 256        // 4 waves; 64 queries per block (1 per lane, x4 scan)
#define SORTT 1024

#define WS_CURV  0
#define WS_RAS2  32768
#define WS_CSUM  131072
#define WS_STAT  131080
#define WS_SORT  131184

typedef unsigned long long ull;

// predicated replace-max insert; serial argmax (R7-measured best)
__device__ __forceinline__ void insertvi(float v, int ix, bool ins,
                                         float (&md)[KNN], int (&mi)[KNN],
                                         float& maxv, int& maxp) {
#pragma unroll
    for (int k = 0; k < KNN; k++) {
        bool sel = ins && (k == maxp);
        md[k] = sel ? v : md[k];
        mi[k] = sel ? ix : mi[k];
    }
    maxv = md[0]; maxp = 0;
#pragma unroll
    for (int k = 1; k < KNN; k++) {
        bool g = md[k] > maxv;
        maxv = g ? md[k] : maxv;
        maxp = g ? k : maxp;
    }
}

__device__ __forceinline__ void drain(float* vbuf, int* ibuf, int tid, int& cnt,
                                      float (&md)[KNN], int (&mi)[KNN],
                                      float& maxv, int& maxp,
                                      float& thr, float probeV) {
#pragma unroll
    for (int t = 0; t < CAP; t++) {
        if (__any(t < cnt)) {
            float d = vbuf[t * BLKT + tid];
            int ix = ibuf[t * BLKT + tid];
            bool ins = (t < cnt) && (d < maxv);
            if (__any(ins)) insertvi(d, ix, ins, md, mi, maxv, maxp);
        }
    }
    cnt = 0;
    thr = fminf(maxv, probeV);
}

// scan one 64-candidate chunk starting at sorted rank cbase
__device__ __forceinline__ void scan_chunk(const float4* pts, int cbase, float4 qp,
                                           float* vbuf, int* ibuf, int tid, int& cnt,
                                           float (&md)[KNN], int (&mi)[KNN],
                                           float& maxv, int& maxp,
                                           float& thr, float probeV) {
    float4 cc[4];
#pragma unroll
    for (int u = 0; u < 4; u++) cc[u] = pts[cbase + u];
    for (int m = 0; m < 64; m += 4) {
        float4 cu[4];
#pragma unroll
        for (int u = 0; u < 4; u++) cu[u] = cc[u];
        int mn = (m + 4 < 64) ? (m + 4) : 0;     // last prefetch redundant
#pragma unroll
        for (int u = 0; u < 4; u++) cc[u] = pts[cbase + mn + u];
#pragma unroll
        for (int u = 0; u < 4; u++) {
            float4 c = cu[u];
            float dx = qp.x - c.x, dy = qp.y - c.y, dz = qp.z - c.z;
            float d2 = dx * dx + dy * dy + dz * dz;
            if (d2 < thr) {
                vbuf[cnt * BLKT + tid] = d2;
                ibuf[cnt * BLKT + tid] = cbase + m + u;
                cnt++;
            }
        }
        if (__any(cnt > CAP - 4)) drain(vbuf, ibuf, tid, cnt, md, mi, maxv, maxp, thr, probeV);
    }
    drain(vbuf, ibuf, tid, cnt, md, mi, maxv, maxp, thr, probeV);
}

// ---------------- presort: per-batch bitonic by x + double stats -----------
__global__ __launch_bounds__(SORTT) void presort_kernel(const float* __restrict__ xyz,
                                                        float* __restrict__ ws) {
    __shared__ ull keys[NPTS];                   // 32 KB
    __shared__ double dst[96];
    int b = blockIdx.x;
    int tid = threadIdx.x;
    const float* base = xyz + b * NPTS * 3;

    double sx = 0, sy = 0, sz = 0, qxx = 0, qyy = 0, qzz = 0;
    for (int p = tid; p < NPTS; p += SORTT) {
        double x = (double)base[p * 3], y = (double)base[p * 3 + 1], z = (double)base[p * 3 + 2];
        sx += x; sy += y; sz += z; qxx += x * x; qyy += y * y; qzz += z * z;
    }
    for (int off = 32; off > 0; off >>= 1) {
        sx += __shfl_down(sx, off);  sy += __shfl_down(sy, off);
        sz += __shfl_down(sz, off);  qxx += __shfl_down(qxx, off);
        qyy += __shfl_down(qyy, off); qzz += __shfl_down(qzz, off);
    }
    int wid = tid >> 6;
    if ((tid & 63) == 0) {
        dst[wid * 6 + 0] = sx;  dst[wid * 6 + 1] = sy;  dst[wid * 6 + 2] = sz;
        dst[wid * 6 + 3] = qxx; dst[wid * 6 + 4] = qyy; dst[wid * 6 + 5] = qzz;
    }
    __syncthreads();
    if (tid == 0) {
        double* wd = (double*)(ws + WS_STAT);
        for (int q = 0; q < 6; q++) {
            double a = 0.0;
            for (int w = 0; w < 16; w++) a += dst[w * 6 + q];
            wd[b * 6 + q] = a;
        }
    }

    // keys: order-preserving uint of x, payload = orig idx
    for (int r = tid; r < NPTS; r += SORTT) {
        unsigned u = __float_as_uint(base[r * 3]);
        u = (u >> 31) ? ~u : (u | 0x80000000u);
        keys[r] = ((ull)u << 32) | (unsigned)r;
    }
    __syncthreads();

    for (int k = 2; k <= NPTS; k <<= 1) {
        for (int j = k >> 1; j > 0; j >>= 1) {
            for (int i = tid; i < NPTS; i += SORTT) {
                int l = i ^ j;
                if (l > i) {
                    ull a = keys[i], c = keys[l];
                    bool up = ((i & k) == 0);
                    if ((a > c) == up) { keys[i] = c; keys[l] = a; }
                }
            }
            __syncthreads();
        }
    }

    float4* out4 = (float4*)(ws + WS_SORT) + b * NPTS;
    for (int r = tid; r < NPTS; r += SORTT) {
        int i = (int)(keys[r] & 0xffffffffULL);
        const float* pp = base + 3 * i;
        out4[r] = make_float4(pp[0], pp[1], pp[2], __int_as_float(i));
    }
}

// ---------------- 3x3 symmetric eigensolve (double, trig method) -----------
__device__ __forceinline__ float curv_from_cov(float c00, float c01, float c02,
                                               float c11, float c12, float c22) {
    double a00 = c00, a01 = c01, a02 = c02, a11 = c11, a12 = c12, a22 = c22;
    double tr = a00 + a11 + a22;
    double q  = tr * (1.0 / 3.0);
    double b00 = a00 - q, b11 = a11 - q, b22 = a22 - q;
    double p2 = b00 * b00 + b11 * b11 + b22 * b22
              + 2.0 * (a01 * a01 + a02 * a02 + a12 * a12);
    double lmin;
    if (p2 < 1e-60) {
        lmin = q;
    } else {
        double p  = sqrt(p2 * (1.0 / 6.0));
        double ip = 1.0 / p;
        double m00 = b00 * ip, m11 = b11 * ip, m22 = b22 * ip;
        double m01 = a01 * ip, m02 = a02 * ip, m12 = a12 * ip;
        double det = m00 * (m11 * m22 - m12 * m12)
                   - m01 * (m01 * m22 - m12 * m02)
                   + m02 * (m01 * m12 - m11 * m02);
        double r = 0.5 * det;
        r = r > 1.0 ? 1.0 : (r < -1.0 ? -1.0 : r);
        double phi = acos(r) * (1.0 / 3.0);
        lmin = q + 2.0 * p * cos(phi + 2.0943951023931953);
    }
    return (float)(lmin / (tr + 1e-6));
}

// ---------------- kNN + covariance + curvature + lstd ----------------------
__global__ __launch_bounds__(BLKT, 2) void knn_kernel(float* __restrict__ ws) {
    __shared__ float4 pts[NPTS];                 // 64 KB (sorted by x)
    __shared__ float vbuf[CAP * BLKT];           // 8 KB, transposed slots
    __shared__ int   ibuf[CAP * BLKT];           // 8 KB, transposed slots
    __shared__ float thrbuf[64];
    int b = blockIdx.x >> 6;                     // 64 blocks per batch
    int q = blockIdx.x & 63;                     // home chunk = query group
    int tid = threadIdx.x;
    const float4* sorted = (const float4*)(ws + WS_SORT) + b * NPTS;
    for (int p = tid; p < NPTS; p += BLKT) pts[p] = sorted[p];
    __syncthreads();

    int wv = tid >> 6, lane = tid & 63;
    int rank = q * 64 + lane;                    // this lane's query (all waves)
    float4 qp = pts[rank];
    float xq = qp.x;
    int cb0 = q * 64;

    float md[KNN]; int mi[KNN];
    float maxv = 3.4e38f; int maxp = 0; int cnt = 0;
    float probeV = 3.4e38f, thr;

    if (wv == 0) {
        // ---- home chunk: seed 17 + buffered scan of the rest -------------
#pragma unroll
        for (int k = 0; k < KNN; k++) {
            float4 c = pts[cb0 + k];
            float dx = qp.x - c.x, dy = qp.y - c.y, dz = qp.z - c.z;
            md[k] = dx * dx + dy * dy + dz * dz;
            mi[k] = cb0 + k;
        }
        maxv = md[0]; maxp = 0;
#pragma unroll
        for (int k = 1; k < KNN; k++) {
            bool g = md[k] > maxv;
            maxv = g ? md[k] : maxv;
            maxp = g ? k : maxp;
        }
        thr = maxv;
#pragma unroll
        for (int m = KNN; m < 20; m++) {         // prologue: align to 4
            float4 c = pts[cb0 + m];
            float dx = qp.x - c.x, dy = qp.y - c.y, dz = qp.z - c.z;
            float d2 = dx * dx + dy * dy + dz * dz;
            if (d2 < thr) {
                vbuf[cnt * BLKT + tid] = d2;
                ibuf[cnt * BLKT + tid] = cb0 + m;
                cnt++;                           // cnt <= 3, no drain needed
            }
        }
        float4 cc[4];
#pragma unroll
        for (int u = 0; u < 4; u++) cc[u] = pts[cb0 + 20 + u];
        for (int m = 20; m < 64; m += 4) {
            float4 cu[4];
#pragma unroll
            for (int u = 0; u < 4; u++) cu[u] = cc[u];
            int mn = (m + 4 < 64) ? (m + 4) : 20;
#pragma unroll
            for (int u = 0; u < 4; u++) cc[u] = pts[cb0 + mn + u];
#pragma unroll
            for (int u = 0; u < 4; u++) {
                float4 c = cu[u];
                float dx = qp.x - c.x, dy = qp.y - c.y, dz = qp.z - c.z;
                float d2 = dx * dx + dy * dy + dz * dz;  // self: +0, kept
                if (d2 < thr) {
                    vbuf[cnt * BLKT + tid] = d2;
                    ibuf[cnt * BLKT + tid] = cb0 + m + u;
                    cnt++;
                }
            }
            if (__any(cnt > CAP - 4)) drain(vbuf, ibuf, tid, cnt, md, mi, maxv, maxp, thr, probeV);
        }
        drain(vbuf, ibuf, tid, cnt, md, mi, maxv, maxp, thr, probeV);
        thrbuf[lane] = thr;                      // share 17th-of-home-chunk
    } else {
#pragma unroll
        for (int k = 0; k < KNN; k++) { md[k] = 3.4e38f; mi[k] = rank; }
    }
    __syncthreads();
    if (wv != 0) {
        probeV = thrbuf[lane];                   // >= true r17 (subset bound)
        thr = probeV;
    }

    // ---- outward disjoint chunks: wave w owns offsets == w (mod 4), wave 0
    //      owns == 0 (mod 4) to offset its home-chunk work ------------------
    int j = (wv == 0) ? 4 : wv;
    bool doneR = false, doneL = false;
    while (!(doneR && doneL)) {
        if (!doneR) {
            int c = q + j;
            if (c > 63) doneR = true;
            else {
                float gap = pts[c * 64].x - xq;  // >= 0 (sorted)
                if (__all(gap * gap >= thr)) doneR = true;   // monotone in j
                else scan_chunk(pts, c * 64, qp, vbuf, ibuf, tid, cnt, md, mi, maxv, maxp, thr, probeV);
            }
        }
        if (!doneL) {
            int c = q - j;
            if (c < 0) doneL = true;
            else {
                float gap = xq - pts[c * 64 + 63].x;
                if (__all(gap * gap >= thr)) doneL = true;
                else scan_chunk(pts, c * 64, qp, vbuf, ibuf, tid, cnt, md, mi, maxv, maxp, thr, probeV);
            }
        }
        j += 4;
    }

    // ---- 3-round LDS merge of the four disjoint lists into wave 0 ---------
    for (int r = 1; r < 4; r++) {
        __syncthreads();
        if (wv == r) {
#pragma unroll
            for (int k = 0; k < KNN; k++) {
                vbuf[lane * KNN + k] = md[k];
                ibuf[lane * KNN + k] = mi[k];
            }
        }
        __syncthreads();
        if (wv == 0) {
#pragma unroll
            for (int k = 0; k < KNN; k++) {
                float d = vbuf[lane * KNN + k];
                int ix = ibuf[lane * KNN + k];
                bool ins = d < maxv;             // INF sentinels skipped
                if (__any(ins)) insertvi(d, ix, ins, md, mi, maxv, maxp);
            }
        }
    }

    // ---- epilogue on wave 0: moments -> curv, rasig2 ----------------------
    if (wv == 0) {
        float s1x = 0, s1y = 0, s1z = 0;
        float cxx = 0, cxy = 0, cxz = 0, cyy = 0, cyz = 0, czz = 0;
#pragma unroll
        for (int k = 0; k < KNN; k++) {
            float4 c = pts[mi[k]];
            float ux = c.x - qp.x, uy = c.y - qp.y, uz = c.z - qp.z;
            s1x += ux; s1y += uy; s1z += uz;
            cxx += ux * ux; cxy += ux * uy; cxz += ux * uz;
            cyy += uy * uy; cyz += uy * uz; czz += uz * uz;
        }
        const float i16 = 1.0f / 16.0f, i15 = 1.0f / 15.0f;
        float mx = s1x * i16, my = s1y * i16, mz = s1z * i16;
        float c00 = (cxx - 16.0f * mx * mx) * i15;
        float c01 = (cxy - 16.0f * mx * my) * i15;
        float c02 = (cxz - 16.0f * mx * mz) * i15;
        float c11 = (cyy - 16.0f * my * my) * i15;
        float c12 = (cyz - 16.0f * my * mz) * i15;
        float c22 = (czz - 16.0f * mz * mz) * i15;

        float curv = curv_from_cov(c00, c01, c02, c11, c12, c22);

        float v0 = c00 > 0.0f ? c00 : 0.0f;
        float v1 = c11 > 0.0f ? c11 : 0.0f;
        float v2 = c22 > 0.0f ? c22 : 0.0f;
        float r2x = 1.0f / (0.3f * (1.0f + sqrtf(v0)) + 1e-6f);
        float r2y = 1.0f / (0.3f * (1.0f + sqrtf(v1)) + 1e-6f);
        float r2z = 1.0f / (0.3f * (1.0f + sqrtf(v2)) + 1e-6f);

        int g = b * NPTS + __float_as_int(qp.w); // original index
        ws[WS_CURV + g] = curv;
        ws[WS_RAS2 + 0 * 32768 + g] = r2x;
        ws[WS_RAS2 + 1 * 32768 + g] = r2y;
        ws[WS_RAS2 + 2 * 32768 + g] = r2z;

        float cs = curv;
        for (int off = 32; off > 0; off >>= 1) cs += __shfl_down(cs, off);
        if (lane == 0) atomicAdd(&ws[WS_CSUM + b], cs);
    }
}

// ---------------- final embedding (parallel finalize folded in) ------------
__global__ void out_kernel(const float* __restrict__ xyz,
                           const float* __restrict__ ws,
                           float* __restrict__ out) {
    __shared__ float sc[3];                      // rasig1, blend, 1-blend
    {
        float part = 0.0f;
        if (threadIdx.x < 24) {
            const double* st = (const double*)(ws + WS_STAT);
            int bb = threadIdx.x / 3, dd = threadIdx.x % 3;
            double s = st[bb * 6 + dd], ss = st[bb * 6 + 3 + dd];
            double var = (ss - s * s / 4096.0) / 4095.0;
            part = (float)sqrt(var > 0.0 ? var : 0.0);
        }
        if (threadIdx.x < 64) {
            for (int off = 32; off > 0; off >>= 1) part += __shfl_down(part, off);
            if (threadIdx.x == 0) {
                float gf = part * (1.0f / 24.0f);
                float denom = 0.3f * (1.0f + gf) + 1e-6f;
                float blend = 1.0f / (1.0f + __expf(-(gf - 0.1f) * 10.0f));
                sc[0] = 1.0f / denom;
                sc[1] = blend;
                sc[2] = 1.0f - blend;
            }
        }
    }
    __syncthreads();

    int idx = blockIdx.x * 256 + (int)threadIdx.x;
    int j = idx & 127;
    int g = idx >> 7;
    int b = g >> 12;
    int f = (j < 127) ? j : 128;                      // OUT_IDX
    int d = (f >= 86) ? 2 : ((f >= 43) ? 1 : 0);
    int t = f - d * 43;
    float fv = (float)((double)(t + 1) * (2.0 / 44.0) - 1.0);  // FEAT_VAL[t]

    float x = xyz[g * 3 + d];
    float rasig1 = sc[0];
    float blend  = sc[1];
    float blendc = sc[2];
    float cmean  = ws[WS_CSUM + b] * (1.0f / 4096.0f);
    float curv   = ws[WS_CURV + g];
    float w = 1.0f / (1.0f + __expf(-10.0f * (curv - cmean)));

    float t1 = (x - fv) * rasig1;
    float e1 = blend * __expf(-0.5f * t1 * t1) + blendc * __cosf(t1);
    float t2 = (x - fv) * ws[WS_RAS2 + (d << 15) + g];
    float e2 = __expf(-0.5f * t2 * t2);
    out[idx] = w * e1 + (1.0f - w) * e2;
}

extern "C" void kernel_launch(void* const* d_in, const int* in_sizes, int n_in,
                              void* d_out, int out_size, void* d_ws, size_t ws_size,
                              hipStream_t stream) {
    const float* xyz = (const float*)d_in[0];
    float* out = (float*)d_out;
    float* ws = (float*)d_ws;

    hipMemsetAsync(ws + WS_CSUM, 0, 8 * sizeof(float), stream);
    presort_kernel<<<8, SORTT, 0, stream>>>(xyz, ws);
    knn_kernel<<<512, BLKT, 0, stream>>>(ws);
    out_kernel<<<out_size / 256, 256, 0, stream>>>(xyz, ws, out);
}

// Round 11
// 274.312 us; speedup vs baseline: 1.9107x; 1.9107x over previous
//
#include <hip/hip_runtime.h>
#include <math.h>

// ---------------------------------------------------------------------------
// EncoderGPECls: kNN(16) -> PCA curvature blend -> adaptive GPE embeddings
// xyz: [8,4096,3] f32  ->  out: [8,4096,128] f32
//
// R11: med3 sorted-insert kNN (branch-free selection), two-pass index recovery.
//   Ascending top-17 update = med3(d2, md[k-1], md[k]) descending + min at
//   slot 0: 18 VALU/candidate, unconditional, no wave sync, no argmax, no
//   append/drain flood (R5-R9's dominant cost: ~70-instr gated inserts).
//   Pass 1: exact 17th-smallest d2 (values only). Pass 2: survivor indices
//   (d2 <= tau*(1+1e-6)) into a tiny transposed u16 buffer; d2 computed by ONE
//   fmaf-explicit helper in all passes (IEEE-fixed, no contraction freedom --
//   avoids R3's bit-exactness trap; margin + exact final select cover it).
//   Final: exact top-17 over <=24 survivors on packed u64 (d2,idx) keys =
//   jax lower-index tie-break (R4-proven). Quarter merge in u64.
//   Shell: R7's (query-per-lane, quarter-per-wave, broadcast b128 reads,
//   512x256 blocks, LDS 64K pts + 12K aux = 77.8K -> 2 blocks/CU).
//
// ws float layout:
//   [0, 32768)            curv per point
//   [32768, 131072)       rasig2 (3 SoA planes of 32768)
//   [131072, 131080)      curv batch sums (atomic, zeroed via memsetAsync)
//   [131080, 131176)      per-batch raw sums as 48 DOUBLES
// ---------------------------------------------------------------------------

#define NPTS 4096
#define KNN 17          // 16 neighbors + self (self contributes zero to sums)
#define SCAP 24         // survivor index slots per lane (transposed u16)
#define BLKT 256        // 4 waves; 64 queries per block (1 per lane)
#define QPB 64

#define WS_CURV  0
#define WS_RAS2  32768
#define WS_CSUM  131072
#define WS_STAT  131080

typedef unsigned long long ull;
#define SENT 0x7F800000FFFFFFFFULL   // (+inf bits, idx=max) sentinel key

// THE single d2 definition: explicit fmaf chain -> identical IEEE ops at every
// call site (no contraction/reassociation freedom). All passes use this.
__device__ __forceinline__ float d2f(float qx, float qy, float qz,
                                     float cx, float cy, float cz) {
    float dx = qx - cx, dy = qy - cy, dz = qz - cz;
    return __builtin_fmaf(dz, dz, __builtin_fmaf(dy, dy, dx * dx));
}

// predicated replace-max insert of packed (d2bits<<32|idx) key; serial argmax
// (R8 showed tree argmax costs +24% issue for nothing at this size)
__device__ __forceinline__ void insertp(ull v, bool ins, ull (&md)[KNN],
                                        ull& maxv, int& maxp) {
#pragma unroll
    for (int k = 0; k < KNN; k++) {
        bool sel = ins && (k == maxp);
        md[k] = sel ? v : md[k];
    }
    maxv = md[0]; maxp = 0;
#pragma unroll
    for (int k = 1; k < KNN; k++) {
        bool g = md[k] > maxv;
        maxv = g ? md[k] : maxv;
        maxp = g ? k : maxp;
    }
}

// ---------------- 3x3 symmetric eigensolve (double, trig method) -----------
__device__ __forceinline__ float curv_from_cov(float c00, float c01, float c02,
                                               float c11, float c12, float c22) {
    double a00 = c00, a01 = c01, a02 = c02, a11 = c11, a12 = c12, a22 = c22;
    double tr = a00 + a11 + a22;
    double q  = tr * (1.0 / 3.0);
    double b00 = a00 - q, b11 = a11 - q, b22 = a22 - q;
    double p2 = b00 * b00 + b11 * b11 + b22 * b22
              + 2.0 * (a01 * a01 + a02 * a02 + a12 * a12);
    double lmin;
    if (p2 < 1e-60) {
        lmin = q;
    } else {
        double p  = sqrt(p2 * (1.0 / 6.0));
        double ip = 1.0 / p;
        double m00 = b00 * ip, m11 = b11 * ip, m22 = b22 * ip;
        double m01 = a01 * ip, m02 = a02 * ip, m12 = a12 * ip;
        double det = m00 * (m11 * m22 - m12 * m12)
                   - m01 * (m01 * m22 - m12 * m02)
                   + m02 * (m01 * m12 - m11 * m02);
        double r = 0.5 * det;
        r = r > 1.0 ? 1.0 : (r < -1.0 ? -1.0 : r);
        double phi = acos(r) * (1.0 / 3.0);
        lmin = q + 2.0 * p * cos(phi + 2.0943951023931953);
    }
    return (float)(lmin / (tr + 1e-6));
}

// ---------------- kNN + covariance + curvature + lstd ----------------------
__global__ __launch_bounds__(BLKT, 2) void knn_kernel(const float* __restrict__ xyz,
                                                      float* __restrict__ ws) {
    __shared__ float4 pts[NPTS];                 // 64 KB
    __shared__ ull aux[1536];                    // 12 KB: stats dbl / u16 survivors / u64 merge
    unsigned short* sbuf = (unsigned short*)aux; // [SCAP][BLKT] transposed slots
    int b = blockIdx.x >> 6;                     // 64 blocks per batch
    int chunk = blockIdx.x & 63;
    int tid = threadIdx.x;
    const float* base = xyz + b * NPTS * 3;
    for (int p = tid; p < NPTS; p += BLKT) {
        pts[p] = make_float4(base[p * 3], base[p * 3 + 1], base[p * 3 + 2], 0.0f);
    }
    __syncthreads();

    // ---- chunk-0 block computes per-batch raw sums in double (into aux) ----
    if (chunk == 0) {
        double sx = 0, sy = 0, sz = 0, qxx = 0, qyy = 0, qzz = 0;
        for (int p = tid; p < NPTS; p += BLKT) {
            float4 c = pts[p];
            sx += (double)c.x; sy += (double)c.y; sz += (double)c.z;
            qxx += (double)c.x * c.x; qyy += (double)c.y * c.y; qzz += (double)c.z * c.z;
        }
        for (int off = 32; off > 0; off >>= 1) {
            sx += __shfl_down(sx, off);  sy += __shfl_down(sy, off);
            sz += __shfl_down(sz, off);  qxx += __shfl_down(qxx, off);
            qyy += __shfl_down(qyy, off); qzz += __shfl_down(qzz, off);
        }
        double* dstat = (double*)aux;
        int wid = tid >> 6;
        if ((tid & 63) == 0) {
            dstat[wid * 6 + 0] = sx;  dstat[wid * 6 + 1] = sy;  dstat[wid * 6 + 2] = sz;
            dstat[wid * 6 + 3] = qxx; dstat[wid * 6 + 4] = qyy; dstat[wid * 6 + 5] = qzz;
        }
        __syncthreads();
        if (tid == 0) {
            double* wd = (double*)(ws + WS_STAT);
            for (int qq = 0; qq < 6; qq++) {
                wd[b * 6 + qq] = dstat[qq] + dstat[6 + qq] + dstat[12 + qq] + dstat[18 + qq];
            }
        }
        __syncthreads();                         // aux free for survivor use
    }

    int wv = tid >> 6;                           // wave id: candidate quarter
    int lane = tid & 63;
    int i = chunk * QPB + lane;                  // this lane's query point
    float4 qp = pts[i];
    int cbase = wv * 1024;                       // this wave's candidate range

    // ---- pass 1: branch-free med3 sorted top-17 (values only) -------------
    float md[KNN];
#pragma unroll
    for (int k = 0; k < KNN; k++) md[k] = 3.4e38f;

    float4 cc[4];
#pragma unroll
    for (int u = 0; u < 4; u++) cc[u] = pts[cbase + u];
    for (int m = 0; m < 1024; m += 4) {
        float4 cu[4];
#pragma unroll
        for (int u = 0; u < 4; u++) cu[u] = cc[u];
        int mn = (m + 4 < 1024) ? (m + 4) : 0;   // last prefetch redundant
#pragma unroll
        for (int u = 0; u < 4; u++) cc[u] = pts[cbase + mn + u];
#pragma unroll
        for (int u = 0; u < 4; u++) {
            float d2 = d2f(qp.x, qp.y, qp.z, cu[u].x, cu[u].y, cu[u].z);
#pragma unroll
            for (int k = KNN - 1; k >= 1; k--)   // descending: reads olds only
                md[k] = __builtin_amdgcn_fmed3f(d2, md[k - 1], md[k]);
            md[0] = fminf(d2, md[0]);
        }
    }
    // md[16] = EXACT 17th-smallest d2 of this quarter; margin for pass 2
    float tau = md[KNN - 1] * 1.000001f;

    // ---- pass 2: survivor index recovery (d2 <= tau), ~17/lane ------------
    int cnt = 0;
#pragma unroll
    for (int u = 0; u < 4; u++) cc[u] = pts[cbase + u];
    for (int m = 0; m < 1024; m += 4) {
        float4 cu[4];
#pragma unroll
        for (int u = 0; u < 4; u++) cu[u] = cc[u];
        int mn = (m + 4 < 1024) ? (m + 4) : 0;
#pragma unroll
        for (int u = 0; u < 4; u++) cc[u] = pts[cbase + mn + u];
#pragma unroll
        for (int u = 0; u < 4; u++) {
            float d2 = d2f(qp.x, qp.y, qp.z, cu[u].x, cu[u].y, cu[u].z);
            if (d2 <= tau) {
                if (cnt < SCAP) sbuf[cnt * BLKT + tid] = (unsigned short)(cbase + m + u);
                cnt++;
            }
        }
    }
    if (cnt > SCAP) cnt = SCAP;                  // ~impossible (ties only)

    // ---- final exact select over survivors: packed u64, jax tie-break -----
    ull k17[KNN];
#pragma unroll
    for (int k = 0; k < KNN; k++) k17[k] = SENT;
    ull maxv = SENT; int maxp = 0;
    for (int t = 0; t < SCAP; t++) {
        if (__any(t < cnt)) {
            int ix = sbuf[t * BLKT + tid];
            float4 c = pts[ix];
            float d2 = d2f(qp.x, qp.y, qp.z, c.x, c.y, c.z);
            ull key = ((ull)__float_as_uint(d2) << 32) | (unsigned)ix;
            bool ins = (t < cnt) && (key < maxv);
            if (__any(ins)) insertp(key, ins, k17, maxv, maxp);
        }
    }

    // ---- 3-round LDS merge of the four quarter-lists into wave 0 ----------
    ull* mg = aux;                               // 64*17 = 1088 ull <= 1536
    for (int r = 1; r < 4; r++) {
        __syncthreads();
        if (wv == r) {
#pragma unroll
            for (int k = 0; k < KNN; k++) mg[lane * KNN + k] = k17[k];
        }
        __syncthreads();
        if (wv == 0) {
#pragma unroll
            for (int k = 0; k < KNN; k++) {
                ull v = mg[lane * KNN + k];
                bool ins = v < maxv;
                if (__any(ins)) insertp(v, ins, k17, maxv, maxp);
            }
        }
    }

    // ---- epilogue on wave 0: moments -> curv, rasig2 ----------------------
    if (wv == 0) {
        float s1x = 0, s1y = 0, s1z = 0;
        float cxx = 0, cxy = 0, cxz = 0, cyy = 0, cyz = 0, czz = 0;
#pragma unroll
        for (int k = 0; k < KNN; k++) {
            int j = (int)(k17[k] & 0xffffffffULL);
            float4 c = pts[j];
            float ux = c.x - qp.x, uy = c.y - qp.y, uz = c.z - qp.z;
            s1x += ux; s1y += uy; s1z += uz;
            cxx += ux * ux; cxy += ux * uy; cxz += ux * uz;
            cyy += uy * uy; cyz += uy * uz; czz += uz * uz;
        }
        const float i16 = 1.0f / 16.0f, i15 = 1.0f / 15.0f;
        float mx = s1x * i16, my = s1y * i16, mz = s1z * i16;
        float c00 = (cxx - 16.0f * mx * mx) * i15;
        float c01 = (cxy - 16.0f * mx * my) * i15;
        float c02 = (cxz - 16.0f * mx * mz) * i15;
        float c11 = (cyy - 16.0f * my * my) * i15;
        float c12 = (cyz - 16.0f * my * mz) * i15;
        float c22 = (czz - 16.0f * mz * mz) * i15;

        float curv = curv_from_cov(c00, c01, c02, c11, c12, c22);

        float v0 = c00 > 0.0f ? c00 : 0.0f;
        float v1 = c11 > 0.0f ? c11 : 0.0f;
        float v2 = c22 > 0.0f ? c22 : 0.0f;
        float r2x = 1.0f / (0.3f * (1.0f + sqrtf(v0)) + 1e-6f);
        float r2y = 1.0f / (0.3f * (1.0f + sqrtf(v1)) + 1e-6f);
        float r2z = 1.0f / (0.3f * (1.0f + sqrtf(v2)) + 1e-6f);

        int g = b * NPTS + i;
        ws[WS_CURV + g] = curv;
        ws[WS_RAS2 + 0 * 32768 + g] = r2x;
        ws[WS_RAS2 + 1 * 32768 + g] = r2y;
        ws[WS_RAS2 + 2 * 32768 + g] = r2z;

        float cs = curv;
        for (int off = 32; off > 0; off >>= 1) cs += __shfl_down(cs, off);
        if (lane == 0) atomicAdd(&ws[WS_CSUM + b], cs);
    }
}

// ---------------- final embedding (scalars computed per-block, PARALLEL) ---
__global__ void out_kernel(const float* __restrict__ xyz,
                           const float* __restrict__ ws,
                           float* __restrict__ out) {
    __shared__ float sc[3];                      // rasig1, blend, 1-blend
    {
        float part = 0.0f;
        if (threadIdx.x < 24) {
            const double* st = (const double*)(ws + WS_STAT);
            int bb = threadIdx.x / 3, dd = threadIdx.x % 3;
            double s = st[bb * 6 + dd], ss = st[bb * 6 + 3 + dd];
            double var = (ss - s * s / 4096.0) / 4095.0;
            part = (float)sqrt(var > 0.0 ? var : 0.0);
        }
        if (threadIdx.x < 64) {
            for (int off = 32; off > 0; off >>= 1) part += __shfl_down(part, off);
            if (threadIdx.x == 0) {
                float gf = part * (1.0f / 24.0f);
                float denom = 0.3f * (1.0f + gf) + 1e-6f;
                float blend = 1.0f / (1.0f + __expf(-(gf - 0.1f) * 10.0f));
                sc[0] = 1.0f / denom;
                sc[1] = blend;
                sc[2] = 1.0f - blend;
            }
        }
    }
    __syncthreads();

    int idx = blockIdx.x * 256 + (int)threadIdx.x;
    int j = idx & 127;
    int g = idx >> 7;
    int b = g >> 12;
    int f = (j < 127) ? j : 128;                      // OUT_IDX
    int d = (f >= 86) ? 2 : ((f >= 43) ? 1 : 0);
    int t = f - d * 43;
    float fv = (float)((double)(t + 1) * (2.0 / 44.0) - 1.0);  // FEAT_VAL[t]

    float x = xyz[g * 3 + d];
    float rasig1 = sc[0];
    float blend  = sc[1];
    float blendc = sc[2];
    float cmean  = ws[WS_CSUM + b] * (1.0f / 4096.0f);
    float curv   = ws[WS_CURV + g];
    float w = 1.0f / (1.0f + __expf(-10.0f * (curv - cmean)));

    float t1 = (x - fv) * rasig1;
    float e1 = blend * __expf(-0.5f * t1 * t1) + blendc * __cosf(t1);
    float t2 = (x - fv) * ws[WS_RAS2 + (d << 15) + g];
    float e2 = __expf(-0.5f * t2 * t2);
    out[idx] = w * e1 + (1.0f - w) * e2;
}

extern "C" void kernel_launch(void* const* d_in, const int* in_sizes, int n_in,
                              void* d_out, int out_size, void* d_ws, size_t ws_size,
                              hipStream_t stream) {
    const float* xyz = (const float*)d_in[0];
    float* out = (float*)d_out;
    float* ws = (float*)d_ws;

    hipMemsetAsync(ws + WS_CSUM, 0, 8 * sizeof(float), stream);
    knn_kernel<<<512, BLKT, 0, stream>>>(xyz, ws);
    out_kernel<<<out_size / 256, 256, 0, stream>>>(xyz, ws, out);
}

// Round 12
// 263.642 us; speedup vs baseline: 1.9881x; 1.0405x over previous
//
#include <hip/hip_runtime.h>
#include <math.h>

// ---------------------------------------------------------------------------
// EncoderGPECls: kNN(16) -> PCA curvature blend -> adaptive GPE embeddings
// xyz: [8,4096,3] f32  ->  out: [8,4096,128] f32
//
// R12 = R11's med3 two-pass selection at DOUBLE occupancy.
//   Diagnosis: R7 (71k instr/wave) and R11 (45k) both ran 222us @ "62%"
//   VALUBusy -- the derived counter uses gfx94x SIMD-16 formulas (4cyc/wave64);
//   on gfx950 SIMD-32 true busy ~31% -> latency-bound at 2 waves/SIMD.
//   Fix: 512-thr blocks (8 waves x 512-candidate eighths), grid 512
//   -> 2 blocks/CU x 8 waves = 4 waves/SIMD (2x R11).
//   LDS 64K pts + 8.7K arena (aliased: stats dbl | pass-2 u8 segment
//   survivors | u16 idx-only merge publishes; receiver re-gathers pts and
//   rebuilds exact u64 keys via the single fmaf-fixed d2f -> bit-identical).
//   3-round tournament merge (1,3,5,7 -> 0,2,4,6; 2,6 -> 0,4; 4 -> 0).
//   Curv sums: non-atomic per-(b,chunk) partials -> memset dispatch deleted
//   (out_kernel wave 0 reduces 512 partials). Two dispatches total.
//   Selection semantics unchanged (exact u64 keys = jax lower-index
//   tie-break; SCAP clamp drops the latest-arriving = highest-index boundary
//   tie, which is what jax drops).
//
// ws float layout:
//   [0, 32768)            curv per point
//   [32768, 131072)       rasig2 (3 SoA planes of 32768)
//   [131072, 131584)      curv partial sums [b][chunk] (8 x 64)
//   [131584, 131680)      per-batch raw sums as 48 DOUBLES
// ---------------------------------------------------------------------------

#define NPTS 4096
#define KNN 17          // 16 neighbors + self (self contributes zero to sums)
#define BLKT 512        // 8 waves; 64 queries per block (1 per lane)
#define QPB 64
#define ESIZE 512       // candidates per wave (eighth)
#define SEG 256         // pass-2 segment size (u8 offsets)
#define SCAP 17         // survivor slots per lane per segment

#define WS_CURV  0
#define WS_RAS2  32768
#define WS_CSUM  131072
#define WS_STAT  131584

typedef unsigned long long ull;
#define SENT 0x7F800000FFFFFFFFULL   // (+inf bits, idx=max) sentinel key

// THE single d2 definition: explicit fmaf chain, identical IEEE ops at every
// call site (no contraction freedom). All passes/merges use this.
__device__ __forceinline__ float d2f(float qx, float qy, float qz,
                                     float cx, float cy, float cz) {
    float dx = qx - cx, dy = qy - cy, dz = qz - cz;
    return __builtin_fmaf(dz, dz, __builtin_fmaf(dy, dy, dx * dx));
}

// predicated replace-max insert of packed (d2bits<<32|idx) key; serial argmax
__device__ __forceinline__ void insertp(ull v, bool ins, ull (&md)[KNN],
                                        ull& maxv, int& maxp) {
#pragma unroll
    for (int k = 0; k < KNN; k++) {
        bool sel = ins && (k == maxp);
        md[k] = sel ? v : md[k];
    }
    maxv = md[0]; maxp = 0;
#pragma unroll
    for (int k = 1; k < KNN; k++) {
        bool g = md[k] > maxv;
        maxv = g ? md[k] : maxv;
        maxp = g ? k : maxp;
    }
}

// ---------------- 3x3 symmetric eigensolve (double, trig method) -----------
__device__ __forceinline__ float curv_from_cov(float c00, float c01, float c02,
                                               float c11, float c12, float c22) {
    double a00 = c00, a01 = c01, a02 = c02, a11 = c11, a12 = c12, a22 = c22;
    double tr = a00 + a11 + a22;
    double q  = tr * (1.0 / 3.0);
    double b00 = a00 - q, b11 = a11 - q, b22 = a22 - q;
    double p2 = b00 * b00 + b11 * b11 + b22 * b22
              + 2.0 * (a01 * a01 + a02 * a02 + a12 * a12);
    double lmin;
    if (p2 < 1e-60) {
        lmin = q;
    } else {
        double p  = sqrt(p2 * (1.0 / 6.0));
        double ip = 1.0 / p;
        double m00 = b00 * ip, m11 = b11 * ip, m22 = b22 * ip;
        double m01 = a01 * ip, m02 = a02 * ip, m12 = a12 * ip;
        double det = m00 * (m11 * m22 - m12 * m12)
                   - m01 * (m01 * m22 - m12 * m02)
                   + m02 * (m01 * m12 - m11 * m02);
        double r = 0.5 * det;
        r = r > 1.0 ? 1.0 : (r < -1.0 ? -1.0 : r);
        double phi = acos(r) * (1.0 / 3.0);
        lmin = q + 2.0 * p * cos(phi + 2.0943951023931953);
    }
    return (float)(lmin / (tr + 1e-6));
}

// ---------------- kNN + covariance + curvature + lstd ----------------------
__global__ __launch_bounds__(BLKT, 4) void knn_kernel(const float* __restrict__ xyz,
                                                      float* __restrict__ ws) {
    __shared__ float4 pts[NPTS];                 // 64 KB
    __shared__ ull aux[1088];                    // 8704 B arena (aliased)
    unsigned char* sbuf = (unsigned char*)aux;   // [SCAP][BLKT] u8 survivors
    unsigned short* pub = (unsigned short*)aux;  // 4 regions x 64x17 u16 idx
    int b = blockIdx.x >> 6;                     // 64 blocks per batch
    int chunk = blockIdx.x & 63;
    int tid = threadIdx.x;
    const float* base = xyz + b * NPTS * 3;
    for (int p = tid; p < NPTS; p += BLKT) {
        pts[p] = make_float4(base[p * 3], base[p * 3 + 1], base[p * 3 + 2], 0.0f);
    }
    __syncthreads();

    // ---- chunk-0 block computes per-batch raw sums in double (into aux) ----
    if (chunk == 0) {
        double sx = 0, sy = 0, sz = 0, qxx = 0, qyy = 0, qzz = 0;
        for (int p = tid; p < NPTS; p += BLKT) {
            float4 c = pts[p];
            sx += (double)c.x; sy += (double)c.y; sz += (double)c.z;
            qxx += (double)c.x * c.x; qyy += (double)c.y * c.y; qzz += (double)c.z * c.z;
        }
        for (int off = 32; off > 0; off >>= 1) {
            sx += __shfl_down(sx, off);  sy += __shfl_down(sy, off);
            sz += __shfl_down(sz, off);  qxx += __shfl_down(qxx, off);
            qyy += __shfl_down(qyy, off); qzz += __shfl_down(qzz, off);
        }
        double* dstat = (double*)aux;
        int wid = tid >> 6;
        if ((tid & 63) == 0) {
            dstat[wid * 6 + 0] = sx;  dstat[wid * 6 + 1] = sy;  dstat[wid * 6 + 2] = sz;
            dstat[wid * 6 + 3] = qxx; dstat[wid * 6 + 4] = qyy; dstat[wid * 6 + 5] = qzz;
        }
        __syncthreads();
        if (tid == 0) {
            double* wd = (double*)(ws + WS_STAT);
            for (int qq = 0; qq < 6; qq++) {
                double a = 0.0;
                for (int w = 0; w < 8; w++) a += dstat[w * 6 + qq];
                wd[b * 6 + qq] = a;
            }
        }
        __syncthreads();                         // aux free for survivor use
    }

    int wv = tid >> 6;                           // wave id: candidate eighth
    int lane = tid & 63;
    int i = chunk * QPB + lane;                  // this lane's query point
    float4 qp = pts[i];
    int cbase = wv * ESIZE;                      // this wave's candidate range

    // ---- pass 1: branch-free med3 sorted top-17 (values only) -------------
    float md[KNN];
#pragma unroll
    for (int k = 0; k < KNN; k++) md[k] = 3.4e38f;

    float4 cc[4];
#pragma unroll
    for (int u = 0; u < 4; u++) cc[u] = pts[cbase + u];
    for (int m = 0; m < ESIZE; m += 4) {
        float4 cu[4];
#pragma unroll
        for (int u = 0; u < 4; u++) cu[u] = cc[u];
        int mn = (m + 4 < ESIZE) ? (m + 4) : 0;  // last prefetch redundant
#pragma unroll
        for (int u = 0; u < 4; u++) cc[u] = pts[cbase + mn + u];
#pragma unroll
        for (int u = 0; u < 4; u++) {
            float d2 = d2f(qp.x, qp.y, qp.z, cu[u].x, cu[u].y, cu[u].z);
#pragma unroll
            for (int k = KNN - 1; k >= 1; k--)   // descending: reads olds only
                md[k] = __builtin_amdgcn_fmed3f(d2, md[k - 1], md[k]);
            md[0] = fminf(d2, md[0]);
        }
    }
    float tau = md[KNN - 1] * 1.000001f;         // exact 17th + margin

    // ---- pass 2 (2 segments of 256): u8 survivor offsets + exact select ---
    ull k17[KNN];
#pragma unroll
    for (int k = 0; k < KNN; k++) k17[k] = SENT;
    ull maxv = SENT; int maxp = 0;

#pragma unroll
    for (int sgi = 0; sgi < 2; sgi++) {
        int segbase = cbase + sgi * SEG;
        int cnt = 0;
#pragma unroll
        for (int u = 0; u < 4; u++) cc[u] = pts[segbase + u];
        for (int m = 0; m < SEG; m += 4) {
            float4 cu[4];
#pragma unroll
            for (int u = 0; u < 4; u++) cu[u] = cc[u];
            int mn = (m + 4 < SEG) ? (m + 4) : 0;
#pragma unroll
            for (int u = 0; u < 4; u++) cc[u] = pts[segbase + mn + u];
#pragma unroll
            for (int u = 0; u < 4; u++) {
                float d2 = d2f(qp.x, qp.y, qp.z, cu[u].x, cu[u].y, cu[u].z);
                if (d2 <= tau) {                 // margin: never misses a true NN
                    if (cnt < SCAP) sbuf[cnt * BLKT + tid] = (unsigned char)(m + u);
                    cnt++;                       // clamp drops latest tie = jax drop
                }
            }
        }
        // drain this segment's survivors into the exact u64 top-17
#pragma unroll
        for (int t = 0; t < SCAP; t++) {
            if (__any(t < cnt)) {
                int ix = segbase + sbuf[t * BLKT + tid];
                float4 c = pts[ix];
                float d2 = d2f(qp.x, qp.y, qp.z, c.x, c.y, c.z);
                ull key = ((ull)__float_as_uint(d2) << 32) | (unsigned)ix;
                bool ins = (t < cnt) && (key < maxv);
                if (__any(ins)) insertp(key, ins, k17, maxv, maxp);
            }
        }
    }

    // ---- 3-round tournament merge (u16 idx publish, keys rebuilt exactly) --
    // regions: r * 1088 u16 entries, entry lane*17+k
    // round 1: 1->0, 3->2, 5->4, 7->6   (regions 0..3)
    __syncthreads();
    if (wv & 1) {
#pragma unroll
        for (int k = 0; k < KNN; k++)
            pub[(wv >> 1) * 1088 + lane * KNN + k] = (unsigned short)(k17[k] & 0xffffULL);
    }
    __syncthreads();
    if (!(wv & 1)) {
        int r = wv >> 1;
#pragma unroll
        for (int k = 0; k < KNN; k++) {
            int ix = pub[r * 1088 + lane * KNN + k];
            float4 c = pts[ix];
            float d2 = d2f(qp.x, qp.y, qp.z, c.x, c.y, c.z);
            ull key = ((ull)__float_as_uint(d2) << 32) | (unsigned)ix;
            bool ins = key < maxv;
            if (__any(ins)) insertp(key, ins, k17, maxv, maxp);
        }
    }
    // round 2: 2->0, 6->4 (regions 0,1)
    __syncthreads();
    if (wv == 2 || wv == 6) {
#pragma unroll
        for (int k = 0; k < KNN; k++)
            pub[(wv >> 2) * 1088 + lane * KNN + k] = (unsigned short)(k17[k] & 0xffffULL);
    }
    __syncthreads();
    if (wv == 0 || wv == 4) {
        int r = wv >> 2;
#pragma unroll
        for (int k = 0; k < KNN; k++) {
            int ix = pub[r * 1088 + lane * KNN + k];
            float4 c = pts[ix];
            float d2 = d2f(qp.x, qp.y, qp.z, c.x, c.y, c.z);
            ull key = ((ull)__float_as_uint(d2) << 32) | (unsigned)ix;
            bool ins = key < maxv;
            if (__any(ins)) insertp(key, ins, k17, maxv, maxp);
        }
    }
    // round 3: 4->0 (region 0)
    __syncthreads();
    if (wv == 4) {
#pragma unroll
        for (int k = 0; k < KNN; k++)
            pub[lane * KNN + k] = (unsigned short)(k17[k] & 0xffffULL);
    }
    __syncthreads();

    // ---- epilogue on wave 0: final merge + moments -> curv, rasig2 --------
    if (wv == 0) {
#pragma unroll
        for (int k = 0; k < KNN; k++) {
            int ix = pub[lane * KNN + k];
            float4 c = pts[ix];
            float d2 = d2f(qp.x, qp.y, qp.z, c.x, c.y, c.z);
            ull key = ((ull)__float_as_uint(d2) << 32) | (unsigned)ix;
            bool ins = key < maxv;
            if (__any(ins)) insertp(key, ins, k17, maxv, maxp);
        }

        float s1x = 0, s1y = 0, s1z = 0;
        float cxx = 0, cxy = 0, cxz = 0, cyy = 0, cyz = 0, czz = 0;
#pragma unroll
        for (int k = 0; k < KNN; k++) {
            int j = (int)(k17[k] & 0xffffffffULL);
            float4 c = pts[j];
            float ux = c.x - qp.x, uy = c.y - qp.y, uz = c.z - qp.z;
            s1x += ux; s1y += uy; s1z += uz;
            cxx += ux * ux; cxy += ux * uy; cxz += ux * uz;
            cyy += uy * uy; cyz += uy * uz; czz += uz * uz;
        }
        const float i16 = 1.0f / 16.0f, i15 = 1.0f / 15.0f;
        float mx = s1x * i16, my = s1y * i16, mz = s1z * i16;
        float c00 = (cxx - 16.0f * mx * mx) * i15;
        float c01 = (cxy - 16.0f * mx * my) * i15;
        float c02 = (cxz - 16.0f * mx * mz) * i15;
        float c11 = (cyy - 16.0f * my * my) * i15;
        float c12 = (cyz - 16.0f * my * mz) * i15;
        float c22 = (czz - 16.0f * mz * mz) * i15;

        float curv = curv_from_cov(c00, c01, c02, c11, c12, c22);

        float v0 = c00 > 0.0f ? c00 : 0.0f;
        float v1 = c11 > 0.0f ? c11 : 0.0f;
        float v2 = c22 > 0.0f ? c22 : 0.0f;
        float r2x = 1.0f / (0.3f * (1.0f + sqrtf(v0)) + 1e-6f);
        float r2y = 1.0f / (0.3f * (1.0f + sqrtf(v1)) + 1e-6f);
        float r2z = 1.0f / (0.3f * (1.0f + sqrtf(v2)) + 1e-6f);

        int g = b * NPTS + i;
        ws[WS_CURV + g] = curv;
        ws[WS_RAS2 + 0 * 32768 + g] = r2x;
        ws[WS_RAS2 + 1 * 32768 + g] = r2y;
        ws[WS_RAS2 + 2 * 32768 + g] = r2z;

        // non-atomic per-(b,chunk) partial sum (no memset dispatch needed)
        float cs = curv;
        for (int off = 32; off > 0; off >>= 1) cs += __shfl_down(cs, off);
        if (lane == 0) ws[WS_CSUM + b * 64 + chunk] = cs;
    }
}

// ---------------- final embedding (scalars + cmeans per-block, parallel) ---
__global__ void out_kernel(const float* __restrict__ xyz,
                           const float* __restrict__ ws,
                           float* __restrict__ out) {
    __shared__ float sc[3];                      // rasig1, blend, 1-blend
    __shared__ float scm[8];                     // per-batch curv mean
    if (threadIdx.x < 64) {
        // gstd from double stats (24 lanes) -> sigmoid scalars
        float part = 0.0f;
        if (threadIdx.x < 24) {
            const double* st = (const double*)(ws + WS_STAT);
            int bb = threadIdx.x / 3, dd = threadIdx.x % 3;
            double s = st[bb * 6 + dd], ss = st[bb * 6 + 3 + dd];
            double var = (ss - s * s / 4096.0) / 4095.0;
            part = (float)sqrt(var > 0.0 ? var : 0.0);
        }
        float p2 = part;
        for (int off = 32; off > 0; off >>= 1) p2 += __shfl_down(p2, off);
        if (threadIdx.x == 0) {
            float gf = p2 * (1.0f / 24.0f);
            float denom = 0.3f * (1.0f + gf) + 1e-6f;
            float blend = 1.0f / (1.0f + __expf(-(gf - 0.1f) * 10.0f));
            sc[0] = 1.0f / denom;
            sc[1] = blend;
            sc[2] = 1.0f - blend;
        }
        // per-batch curv means from 512 partials: lane L sums [L*8, L*8+8)
        float cp = 0.0f;
        const float* pf = ws + WS_CSUM;
#pragma unroll
        for (int t = 0; t < 8; t++) cp += pf[threadIdx.x * 8 + t];
        cp += __shfl_down(cp, 4);
        cp += __shfl_down(cp, 2);
        cp += __shfl_down(cp, 1);
        if ((threadIdx.x & 7) == 0) scm[threadIdx.x >> 3] = cp * (1.0f / 4096.0f);
    }
    __syncthreads();

    int idx = blockIdx.x * 256 + (int)threadIdx.x;
    int j = idx & 127;
    int g = idx >> 7;
    int b = g >> 12;
    int f = (j < 127) ? j : 128;                      // OUT_IDX
    int d = (f >= 86) ? 2 : ((f >= 43) ? 1 : 0);
    int t = f - d * 43;
    float fv = (float)((double)(t + 1) * (2.0 / 44.0) - 1.0);  // FEAT_VAL[t]

    float x = xyz[g * 3 + d];
    float rasig1 = sc[0];
    float blend  = sc[1];
    float blendc = sc[2];
    float cmean  = scm[b];
    float curv   = ws[WS_CURV + g];
    float w = 1.0f / (1.0f + __expf(-10.0f * (curv - cmean)));

    float t1 = (x - fv) * rasig1;
    float e1 = blend * __expf(-0.5f * t1 * t1) + blendc * __cosf(t1);
    float t2 = (x - fv) * ws[WS_RAS2 + (d << 15) + g];
    float e2 = __expf(-0.5f * t2 * t2);
    out[idx] = w * e1 + (1.0f - w) * e2;
}

extern "C" void kernel_launch(void* const* d_in, const int* in_sizes, int n_in,
                              void* d_out, int out_size, void* d_ws, size_t ws_size,
                              hipStream_t stream) {
    const float* xyz = (const float*)d_in[0];
    float* out = (float*)d_out;
    float* ws = (float*)d_ws;

    knn_kernel<<<512, BLKT, 0, stream>>>(xyz, ws);
    out_kernel<<<out_size / 256, 256, 0, stream>>>(xyz, ws, out);
}